// Round 9
// baseline (49004.901 us; speedup 1.0000x reference)
//
#include <hip/hip_runtime.h>
#include <math.h>
#include <stdint.h>

// Three-body RNN: B=32, S=4096, I=64, H=128, O=64
#define NB 32
#define NS 4096
#define NI 64
#define NH 128
#define NO 64
#define RT 256

// h_lds layout: per batch-row, 16 chunks of 8 floats at stride 12 floats
// (2-way bank aliasing only = free; verified: SQ_LDS_BANK_CONFLICT small)
#define CH_STRIDE 12
#define B_STRIDE (16 * CH_STRIDE)   // 192 floats per batch-row

typedef float f4 __attribute__((ext_vector_type(4)));
typedef unsigned int u4 __attribute__((ext_vector_type(4)));

// ---------------------------------------------------------------------------
// Kernel 1: input projection  iw[b][t][h] = sum_i u[b][t][i]*W_in[h][i] + b_in[h]
// ---------------------------------------------------------------------------
__global__ __launch_bounds__(256)
void k_input_proj(const float* __restrict__ u, const float* __restrict__ W_in,
                  const float* __restrict__ b_in, float* __restrict__ iw)
{
    const int gid = blockIdx.x * 256 + threadIdx.x;   // < NB*NS*NH = 2^24
    const int h = gid & (NH - 1);
    const int t = (gid >> 7) & (NS - 1);
    const int b = gid >> 19;
    const f4* ur = reinterpret_cast<const f4*>(u + ((size_t)b * NS + t) * NI);
    const f4* wr = reinterpret_cast<const f4*>(W_in + h * NI);
    float acc = b_in[h];
#pragma unroll
    for (int q = 0; q < NI / 4; ++q) {
        const f4 uv = ur[q], wv = wr[q];
        acc = fmaf(uv[0], wv[0], acc); acc = fmaf(uv[1], wv[1], acc);
        acc = fmaf(uv[2], wv[2], acc); acc = fmaf(uv[3], wv[3], acc);
    }
    iw[gid] = acc;   // gid == ((b*NS)+t)*NH + h
}

// ---------------------------------------------------------------------------
// Kernel 1b: init exchange. hex[par][i][b] epoch-packed; nf = compact notify
// (nf[par][bh][i], u32 epoch per producer block). parity 0 = epoch 0 (ready);
// parity-1 slots stay 0xFF from memset (never match).
// ---------------------------------------------------------------------------
__global__ __launch_bounds__(256)
void k_init_hex(const float* __restrict__ hidden, uint64_t* __restrict__ hex,
                uint32_t* __restrict__ nf)
{
    const int gid = blockIdx.x * 256 + threadIdx.x;   // < NH*NB = 4096
    const int b = gid & (NB - 1);
    const int i = gid >> 5;
    hex[gid] = (uint64_t)__float_as_uint(hidden[b * NH + i]);  // epoch 0 hi
    if (gid < 2 * NH) nf[gid] = 0;   // nf[0][bh][i] = 0 (parity-0 ready)
}

// ---------------------------------------------------------------------------
// Kernel 2: persistent recurrence. Block bi = (i = bi>>1, bh = bi&1).
// ROUND-9: COMPACT-NOTIFY EXCHANGE. r6-r8 showed the spin storm saturates
// the IC slices owning the 512 hex lines (payload cut -> 6%; 7us pipeline
// slack -> no gain): service-rate, not latency or link-BW. New protocol:
// producer stores its 128B data (one 16-lane dwordx2) then ONE 4B notify
// word (hint, no waitcnt). Consumers spin on the 512B notify array only
// (8 lines/block/sweep vs 256 -> ~30x less sustained IC pressure,
// s_sleep 2 backoff), then fetch their data line ONCE and verify the 8
// embedded epochs (retry on the rare notify-outruns-data; correctness
// never relies on store ordering). T3 in 16 NAMED f4 regs (proven r5-r8);
// stride-12 LDS, coalesced release, iw prefetch (proven).
// ---------------------------------------------------------------------------
__global__ __launch_bounds__(RT)
__attribute__((amdgpu_waves_per_eu(1, 1)))
void k_recur(const float* __restrict__ T3, const float* __restrict__ bias_t,
             float* __restrict__ r_region,   // [B][S][H]: iw on entry, h on exit
             float* __restrict__ h_last,     // [B][H]
             uint64_t* hex,                  // [2][NH][NB] epoch-packed
             uint32_t* nf)                   // [2][2][NH] notify epochs
{
    const int bi  = blockIdx.x;
    const int i   = bi >> 1;
    const int bh  = bi & 1;
    const int B0  = bh * 16;
    const int tid = threadIdx.x;
    const int jg  = tid >> 4;          // 0..15 (j-group for compute)
    const int kg  = tid & 15;          // 0..15 (k-group for compute)
    const int w   = tid >> 6;          // wave 0..3

    // poll mapping: thread owns line (i_pol, oct) = 8 consecutive b slots
    const int ipol = tid >> 1;                 // 0..127
    const int oct  = 2 * bh + (tid & 1);       // 0..3 (global b-oct)
    const int bl0  = (tid & 1) * 8;            // local b of first slot

    __shared__ float h_lds[16 * B_STRIDE];   // 12 KB
    __shared__ float redbuf[4][16];
    __shared__ float lds_pad[20480];         // 80 KB: pins 1-block/CU budget

    // ---- T3 tile -> 16 NAMED f4 registers via volatile asm loads ----
    const float* base = T3 + (size_t)i * NH * NH + (size_t)(jg * 8) * NH + kg * 8;
    f4 t3_0, t3_1, t3_2, t3_3, t3_4, t3_5, t3_6, t3_7;
    f4 t3_8, t3_9, t3_10, t3_11, t3_12, t3_13, t3_14, t3_15;
#define T3LOAD(dst, fofs) \
    asm volatile("global_load_dwordx4 %0, %1, off" \
                 : "=v"(dst) : "v"(base + (fofs)) : "memory")
    T3LOAD(t3_0,  0 * NH);     T3LOAD(t3_1,  0 * NH + 4);
    T3LOAD(t3_2,  1 * NH);     T3LOAD(t3_3,  1 * NH + 4);
    T3LOAD(t3_4,  2 * NH);     T3LOAD(t3_5,  2 * NH + 4);
    T3LOAD(t3_6,  3 * NH);     T3LOAD(t3_7,  3 * NH + 4);
    T3LOAD(t3_8,  4 * NH);     T3LOAD(t3_9,  4 * NH + 4);
    T3LOAD(t3_10, 5 * NH);     T3LOAD(t3_11, 5 * NH + 4);
    T3LOAD(t3_12, 6 * NH);     T3LOAD(t3_13, 6 * NH + 4);
    T3LOAD(t3_14, 7 * NH);     T3LOAD(t3_15, 7 * NH + 4);
#undef T3LOAD
    asm volatile("s_waitcnt vmcnt(0)" ::: "memory");
    __builtin_amdgcn_sched_barrier(0);

    const float bias = bias_t[i];
    // runtime-impossible guard keeps lds_pad allocated without executing
    if (bias > 1.0e30f) lds_pad[tid] = bias;

    float iw_cur = 0.f;
    if (tid < 16)
        iw_cur = r_region[((size_t)(B0 + tid) * NS + 0) * NH + i];

    for (int t = 0; t < NS; ++t) {
        const uint32_t et = (uint32_t)t;
        // ---- phase 1: spin on the compact notify word gating OWN line ----
        {
            const uint32_t* nfp = nf + ((size_t)(t & 1) * 2 + bh) * NH + ipol;
            uint32_t e;
            for (;;) {
                asm volatile("global_load_dword %0, %1, off sc0 sc1\n\t"
                             "s_waitcnt vmcnt(0)"
                             : "=v"(e) : "v"(nfp) : "memory");
                if (e == et) break;
                asm volatile("s_sleep 2");
            }
        }
        // ---- phase 2: fetch own 64B line once, verify embedded epochs ----
        {
            const uint64_t* src = hex + ((size_t)(t & 1) * NH + ipol) * NB + oct * 8;
            u4 q0, q1, q2, q3;
            for (;;) {
                asm volatile(
                    "global_load_dwordx4 %0, %4, off sc0 sc1\n\t"
                    "global_load_dwordx4 %1, %4, off offset:16 sc0 sc1\n\t"
                    "global_load_dwordx4 %2, %4, off offset:32 sc0 sc1\n\t"
                    "global_load_dwordx4 %3, %4, off offset:48 sc0 sc1\n\t"
                    "s_waitcnt vmcnt(0)"
                    : "=&v"(q0), "=&v"(q1), "=&v"(q2), "=&v"(q3)
                    : "v"(src) : "memory");
                if (q0[1] == et && q0[3] == et && q1[1] == et && q1[3] == et &&
                    q2[1] == et && q2[3] == et && q3[1] == et && q3[3] == et)
                    break;
                asm volatile("s_sleep 1");
            }
            // scatter 8 b-rows of h[i=ipol] into LDS
            float* dst = h_lds + bl0 * B_STRIDE
                       + (ipol >> 3) * CH_STRIDE + (ipol & 7);
            dst[0 * B_STRIDE] = __uint_as_float(q0[0]);
            dst[1 * B_STRIDE] = __uint_as_float(q0[2]);
            dst[2 * B_STRIDE] = __uint_as_float(q1[0]);
            dst[3 * B_STRIDE] = __uint_as_float(q1[2]);
            dst[4 * B_STRIDE] = __uint_as_float(q2[0]);
            dst[5 * B_STRIDE] = __uint_as_float(q2[2]);
            dst[6 * B_STRIDE] = __uint_as_float(q3[0]);
            dst[7 * B_STRIDE] = __uint_as_float(q3[2]);
        }
        __syncthreads();

        // ---- compute: 16 batches, T3 in named regs, explicit unroll ----
#define JJBODY(tA, tB, HJV) \
        { float s0 = 0.f, s1 = 0.f; \
          s0 = fmaf(tA[0], hk0[0], s0); s1 = fmaf(tA[1], hk0[1], s1); \
          s0 = fmaf(tA[2], hk0[2], s0); s1 = fmaf(tA[3], hk0[3], s1); \
          s0 = fmaf(tB[0], hk1[0], s0); s1 = fmaf(tB[1], hk1[1], s1); \
          s0 = fmaf(tB[2], hk1[2], s0); s1 = fmaf(tB[3], hk1[3], s1); \
          acc = fmaf(HJV, s0 + s1, acc); }
#pragma unroll 4
        for (int b = 0; b < 16; ++b) {
            const float* row = h_lds + b * B_STRIDE;
            const f4 hj0 = *reinterpret_cast<const f4*>(row + jg * CH_STRIDE);
            const f4 hj1 = *reinterpret_cast<const f4*>(row + jg * CH_STRIDE + 4);
            const f4 hk0 = *reinterpret_cast<const f4*>(row + kg * CH_STRIDE);
            const f4 hk1 = *reinterpret_cast<const f4*>(row + kg * CH_STRIDE + 4);
            float acc = 0.f;
            JJBODY(t3_0,  t3_1,  hj0[0]);
            JJBODY(t3_2,  t3_3,  hj0[1]);
            JJBODY(t3_4,  t3_5,  hj0[2]);
            JJBODY(t3_6,  t3_7,  hj0[3]);
            JJBODY(t3_8,  t3_9,  hj1[0]);
            JJBODY(t3_10, t3_11, hj1[1]);
            JJBODY(t3_12, t3_13, hj1[2]);
            JJBODY(t3_14, t3_15, hj1[3]);
            acc += __shfl_xor(acc, 1);  acc += __shfl_xor(acc, 2);
            acc += __shfl_xor(acc, 4);  acc += __shfl_xor(acc, 8);
            acc += __shfl_xor(acc, 16); acc += __shfl_xor(acc, 32);
            if ((tid & 63) == b) redbuf[w][b] = acc;
        }
#undef JJBODY
        __syncthreads();

        // ---- finalize: 16 lanes of wave 0, one batch each ----
        if (tid < 16) {
            const int b = B0 + tid;
            const float s = redbuf[0][tid] + redbuf[1][tid]
                          + redbuf[2][tid] + redbuf[3][tid];
            const float hn = tanhf(s + bias + iw_cur);
            // data release: 16 lanes -> 128B contiguous (2 lines), one instr
            const uint64_t pv = ((uint64_t)(uint32_t)(t + 1) << 32)
                              | (uint64_t)__float_as_uint(hn);
            uint64_t* dstp = hex + ((size_t)((t + 1) & 1) * NH + i) * NB + b;
            asm volatile("global_store_dwordx2 %0, %1, off sc0 sc1"
                         :: "v"(dstp), "v"(pv) : "memory");
            // notify hint (issued after data in program order; consumers
            // verify embedded epochs, so ordering is not load-bearing)
            if (tid == 0) {
                uint32_t* nfp = nf + ((size_t)((t + 1) & 1) * 2 + bh) * NH + i;
                const uint32_t ne = (uint32_t)(t + 1);
                asm volatile("global_store_dword %0, %1, off sc0 sc1"
                             :: "v"(nfp), "v"(ne) : "memory");
            }
            const size_t ridx = ((size_t)b * NS + t) * NH + i;
            r_region[ridx] = hn;
            if (t + 1 < NS) iw_cur = r_region[ridx + NH];  // prefetch next iw
            if (t == NS - 1) h_last[(size_t)b * NH + i] = hn;
        }
        // no barrier: next phase only rewrites h_lds (reads done pre-barrier);
        // redbuf rewritten only after the next post-fetch __syncthreads.
    }
}

// ---------------------------------------------------------------------------
// Kernel 3: output projection  out[b][s][o] = sum_h r[b][s][h]*W_out[o][h] + b_out[o]
// ---------------------------------------------------------------------------
__global__ __launch_bounds__(256)
void k_out_proj(const float* __restrict__ r, const float* __restrict__ W_out,
                const float* __restrict__ b_out, float* __restrict__ out)
{
    const int gid = blockIdx.x * 256 + threadIdx.x;   // < NB*NS*NO = 2^23
    const int o = gid & (NO - 1);
    const int s = (gid >> 6) & (NS - 1);
    const int b = gid >> 18;
    const f4* rr = reinterpret_cast<const f4*>(r + ((size_t)b * NS + s) * NH);
    const f4* wr = reinterpret_cast<const f4*>(W_out + o * NH);
    float acc = b_out[o];
#pragma unroll
    for (int q = 0; q < NH / 4; ++q) {
        const f4 rv = rr[q], wv = wr[q];
        acc = fmaf(rv[0], wv[0], acc); acc = fmaf(rv[1], wv[1], acc);
        acc = fmaf(rv[2], wv[2], acc); acc = fmaf(rv[3], wv[3], acc);
    }
    out[gid] = acc;   // gid == ((b*NS)+s)*NO + o
}

// ---------------------------------------------------------------------------
extern "C" void kernel_launch(void* const* d_in, const int* in_sizes, int n_in,
                              void* d_out, int out_size, void* d_ws, size_t ws_size,
                              hipStream_t stream)
{
    const float* u      = (const float*)d_in[0];
    const float* hidden = (const float*)d_in[1];
    const float* W_in   = (const float*)d_in[2];
    const float* b_in   = (const float*)d_in[3];
    const float* T3     = (const float*)d_in[4];
    const float* bias_t = (const float*)d_in[5];
    const float* W_out  = (const float*)d_in[6];
    const float* b_out  = (const float*)d_in[7];

    float* out_f  = (float*)d_out;
    float* out_y  = out_f;                                  // [B][S][O]
    float* out_hl = out_f + (size_t)NB * NS * NO;           // [B][H]
    float* out_r  = out_hl + (size_t)NB * NH;               // [B][S][H]

    uint64_t* hex = (uint64_t*)d_ws;                        // [2][NH][NB] = 64 KB
    uint32_t* nf  = (uint32_t*)((char*)d_ws + 2 * NB * NH * 8);  // 2 KB

    // reset exchange + notify every call (graph-replay safe):
    // 0xFF -> parity-1 epochs never match; init kernel fills parity 0.
    hipMemsetAsync(hex, 0xFF, 2 * NB * NH * 8 + 2 * 2 * NH * 4, stream);
    k_init_hex<<<(NB * NH) / 256, 256, 0, stream>>>(hidden, hex, nf);

    k_input_proj<<<(NB * NS * NH) / 256, 256, 0, stream>>>(u, W_in, b_in, out_r);
    k_recur<<<2 * NH, RT, 0, stream>>>(T3, bias_t, out_r, out_hl, hex, nf);
    k_out_proj<<<(NB * NS * NO) / 256, 256, 0, stream>>>(out_r, W_out, b_out, out_y);
}

// Round 14
// 39266.891 us; speedup vs baseline: 1.2480x; 1.2480x over previous
//
#include <hip/hip_runtime.h>
#include <math.h>
#include <stdint.h>

// Three-body RNN: B=32, S=4096, I=64, H=128, O=64
#define NB 32
#define NS 4096
#define NI 64
#define NH 128
#define NO 64
#define RT 256

// Spin-guard: converts any stall into a fast diagnosable wrong-answer
// instead of a device-wedging hang. ~4M sweeps ~ 0.5s.
#define SPIN_MAX (1 << 22)

// h_lds layout: per batch, 16 chunks of 8 floats at stride 12 floats
// (2-way bank aliasing only = free; verified r2-r9)
#define CH_STRIDE 12
#define B_STRIDE (16 * CH_STRIDE)   // 192 floats per batch

typedef float f4 __attribute__((ext_vector_type(4)));
typedef unsigned int u4 __attribute__((ext_vector_type(4)));

// ---------------------------------------------------------------------------
// Kernel 1: input projection  iw[b][t][h] = sum_i u[b][t][i]*W_in[h][i] + b_in[h]
// ---------------------------------------------------------------------------
__global__ __launch_bounds__(256)
void k_input_proj(const float* __restrict__ u, const float* __restrict__ W_in,
                  const float* __restrict__ b_in, float* __restrict__ iw)
{
    const int gid = blockIdx.x * 256 + threadIdx.x;   // < NB*NS*NH = 2^24
    const int h = gid & (NH - 1);
    const int t = (gid >> 7) & (NS - 1);
    const int b = gid >> 19;
    const f4* ur = reinterpret_cast<const f4*>(u + ((size_t)b * NS + t) * NI);
    const f4* wr = reinterpret_cast<const f4*>(W_in + h * NI);
    float acc = b_in[h];
#pragma unroll
    for (int q = 0; q < NI / 4; ++q) {
        const f4 uv = ur[q], wv = wr[q];
        acc = fmaf(uv[0], wv[0], acc); acc = fmaf(uv[1], wv[1], acc);
        acc = fmaf(uv[2], wv[2], acc); acc = fmaf(uv[3], wv[3], acc);
    }
    iw[gid] = acc;   // gid == ((b*NS)+t)*NH + h
}

// ---------------------------------------------------------------------------
// Kernel 1b: init epoch-packed exchange, layout hex[par][i][b].
// parity 0 = (h0, epoch 0); parity-1 slots pre-memset to 0xFF (never match).
// ---------------------------------------------------------------------------
__global__ __launch_bounds__(256)
void k_init_hex(const float* __restrict__ hidden, uint64_t* __restrict__ hex)
{
    const int gid = blockIdx.x * 256 + threadIdx.x;   // < NH*NB = 4096
    const int b = gid & (NB - 1);
    const int i = gid >> 5;
    hex[gid] = (uint64_t)__float_as_uint(hidden[b * NH + i]);  // epoch 0 hi
}

// ---------------------------------------------------------------------------
// Kernel 2: persistent recurrence — EXACT r7 structure (best passing config:
// 35.0ms k_recur, stable across 5 profiled runs) + spin-guards.
// Block bi = (i = bi>>1, bh = bi&1). T3 tile in 16 NAMED f4 regs (asm
// execute-once; VGPR=132 proven). Two-phase poll: cheap 8B slot-0 spin with
// s_sleep backoff, then one 64B line fetch verifying all 8 embedded epochs.
// All exchange at sc0 sc1 (system scope). Epoch-packed parity double-buffer.
// ---------------------------------------------------------------------------
__global__ __launch_bounds__(RT)
__attribute__((amdgpu_waves_per_eu(1, 1)))
void k_recur(const float* __restrict__ T3, const float* __restrict__ bias_t,
             float* __restrict__ r_region,   // [B][S][H]: iw on entry, h on exit
             float* __restrict__ h_last,     // [B][H]
             uint64_t* hex)                  // [2][NH][NB] epoch-packed
{
    const int bi  = blockIdx.x;
    const int i   = bi >> 1;
    const int bh  = bi & 1;
    const int B0  = bh * 16;
    const int tid = threadIdx.x;
    const int jg  = tid >> 4;          // 0..15 (j-group for compute)
    const int kg  = tid & 15;          // 0..15 (k-group for compute)
    const int w   = tid >> 6;          // wave 0..3

    // poll mapping: thread owns line (i_pol, oct) = 8 consecutive b slots
    const int ipol = tid >> 1;                 // 0..127
    const int oct  = 2 * bh + (tid & 1);       // 0..3 (global b-oct)
    const int bl0  = (tid & 1) * 8;            // local b of first slot

    __shared__ float h_lds[16 * B_STRIDE];   // 12 KB
    __shared__ float redbuf[4][16];
    __shared__ float lds_pad[20480];         // pins 1-block/CU reg budget

    // ---- T3 tile -> 16 NAMED f4 registers via volatile asm loads ----
    const float* base = T3 + (size_t)i * NH * NH + (size_t)(jg * 8) * NH + kg * 8;
    f4 t3_0, t3_1, t3_2, t3_3, t3_4, t3_5, t3_6, t3_7;
    f4 t3_8, t3_9, t3_10, t3_11, t3_12, t3_13, t3_14, t3_15;
#define T3LOAD(dst, fofs) \
    asm volatile("global_load_dwordx4 %0, %1, off" \
                 : "=v"(dst) : "v"(base + (fofs)) : "memory")
    T3LOAD(t3_0,  0 * NH);     T3LOAD(t3_1,  0 * NH + 4);
    T3LOAD(t3_2,  1 * NH);     T3LOAD(t3_3,  1 * NH + 4);
    T3LOAD(t3_4,  2 * NH);     T3LOAD(t3_5,  2 * NH + 4);
    T3LOAD(t3_6,  3 * NH);     T3LOAD(t3_7,  3 * NH + 4);
    T3LOAD(t3_8,  4 * NH);     T3LOAD(t3_9,  4 * NH + 4);
    T3LOAD(t3_10, 5 * NH);     T3LOAD(t3_11, 5 * NH + 4);
    T3LOAD(t3_12, 6 * NH);     T3LOAD(t3_13, 6 * NH + 4);
    T3LOAD(t3_14, 7 * NH);     T3LOAD(t3_15, 7 * NH + 4);
#undef T3LOAD
    asm volatile("s_waitcnt vmcnt(0)" ::: "memory");
    __builtin_amdgcn_sched_barrier(0);

    const float bias = bias_t[i];
    // runtime-impossible guard keeps lds_pad allocated without executing
    if (bias > 1.0e30f) lds_pad[tid] = bias;

    float iw_cur = 0.f;
    if (tid < 16)
        iw_cur = r_region[((size_t)(B0 + tid) * NS + 0) * NH + i];

    for (int t = 0; t < NS; ++t) {
        // ---- two-phase poll of own 64B line (system scope) ----
        {
            const uint64_t* src = hex + ((size_t)(t & 1) * NH + ipol) * NB + oct * 8;
            const uint32_t et = (uint32_t)t;
            // phase 1: cheap 8B spin on slot-0 epoch, s_sleep backoff
            uint64_t s0v;
            for (int spin = 0;; ++spin) {
                asm volatile("global_load_dwordx2 %0, %1, off sc0 sc1\n\t"
                             "s_waitcnt vmcnt(0)"
                             : "=v"(s0v) : "v"(src) : "memory");
                if (((uint32_t)(s0v >> 32) == et) | (spin > SPIN_MAX)) break;
                asm volatile("s_sleep 1");
            }
            // phase 2: full line, verify ALL epochs (no atomicity assumption)
            u4 q0, q1, q2, q3;
            for (int spin = 0;; ++spin) {
                asm volatile(
                    "global_load_dwordx4 %0, %4, off sc0 sc1\n\t"
                    "global_load_dwordx4 %1, %4, off offset:16 sc0 sc1\n\t"
                    "global_load_dwordx4 %2, %4, off offset:32 sc0 sc1\n\t"
                    "global_load_dwordx4 %3, %4, off offset:48 sc0 sc1\n\t"
                    "s_waitcnt vmcnt(0)"
                    : "=&v"(q0), "=&v"(q1), "=&v"(q2), "=&v"(q3)
                    : "v"(src) : "memory");
                if ((q0[1] == et && q0[3] == et && q1[1] == et && q1[3] == et &&
                     q2[1] == et && q2[3] == et && q3[1] == et && q3[3] == et)
                    | (spin > SPIN_MAX))
                    break;
                asm volatile("s_sleep 1");
            }
            // scatter 8 b-rows of h[i=ipol] into LDS
            float* dst = h_lds + bl0 * B_STRIDE
                       + (ipol >> 3) * CH_STRIDE + (ipol & 7);
            dst[0 * B_STRIDE] = __uint_as_float(q0[0]);
            dst[1 * B_STRIDE] = __uint_as_float(q0[2]);
            dst[2 * B_STRIDE] = __uint_as_float(q1[0]);
            dst[3 * B_STRIDE] = __uint_as_float(q1[2]);
            dst[4 * B_STRIDE] = __uint_as_float(q2[0]);
            dst[5 * B_STRIDE] = __uint_as_float(q2[2]);
            dst[6 * B_STRIDE] = __uint_as_float(q3[0]);
            dst[7 * B_STRIDE] = __uint_as_float(q3[2]);
        }
        __syncthreads();

        // ---- compute: 16 batches, T3 in named regs, explicit unroll ----
#define JJBODY(tA, tB, HJV) \
        { float s0 = 0.f, s1 = 0.f; \
          s0 = fmaf(tA[0], hk0[0], s0); s1 = fmaf(tA[1], hk0[1], s1); \
          s0 = fmaf(tA[2], hk0[2], s0); s1 = fmaf(tA[3], hk0[3], s1); \
          s0 = fmaf(tB[0], hk1[0], s0); s1 = fmaf(tB[1], hk1[1], s1); \
          s0 = fmaf(tB[2], hk1[2], s0); s1 = fmaf(tB[3], hk1[3], s1); \
          acc = fmaf(HJV, s0 + s1, acc); }
#pragma unroll 4
        for (int b = 0; b < 16; ++b) {
            const float* row = h_lds + b * B_STRIDE;
            const f4 hj0 = *reinterpret_cast<const f4*>(row + jg * CH_STRIDE);
            const f4 hj1 = *reinterpret_cast<const f4*>(row + jg * CH_STRIDE + 4);
            const f4 hk0 = *reinterpret_cast<const f4*>(row + kg * CH_STRIDE);
            const f4 hk1 = *reinterpret_cast<const f4*>(row + kg * CH_STRIDE + 4);
            float acc = 0.f;
            JJBODY(t3_0,  t3_1,  hj0[0]);
            JJBODY(t3_2,  t3_3,  hj0[1]);
            JJBODY(t3_4,  t3_5,  hj0[2]);
            JJBODY(t3_6,  t3_7,  hj0[3]);
            JJBODY(t3_8,  t3_9,  hj1[0]);
            JJBODY(t3_10, t3_11, hj1[1]);
            JJBODY(t3_12, t3_13, hj1[2]);
            JJBODY(t3_14, t3_15, hj1[3]);
            acc += __shfl_xor(acc, 1);  acc += __shfl_xor(acc, 2);
            acc += __shfl_xor(acc, 4);  acc += __shfl_xor(acc, 8);
            acc += __shfl_xor(acc, 16); acc += __shfl_xor(acc, 32);
            if ((tid & 63) == b) redbuf[w][b] = acc;
        }
#undef JJBODY
        __syncthreads();

        // ---- finalize: 16 lanes of wave 0, one batch each ----
        if (tid < 16) {
            const int b = B0 + tid;
            const float s = redbuf[0][tid] + redbuf[1][tid]
                          + redbuf[2][tid] + redbuf[3][tid];
            const float hn = tanhf(s + bias + iw_cur);
            // coalesced contiguous release: 16 lanes -> 2 full 64B lines,
            // system scope (write-through to coherence point)
            const uint64_t pv = ((uint64_t)(uint32_t)(t + 1) << 32)
                              | (uint64_t)__float_as_uint(hn);
            uint64_t* dstp = hex + ((size_t)((t + 1) & 1) * NH + i) * NB + b;
            asm volatile("global_store_dwordx2 %0, %1, off sc0 sc1"
                         :: "v"(dstp), "v"(pv) : "memory");
            const size_t ridx = ((size_t)b * NS + t) * NH + i;
            r_region[ridx] = hn;
            if (t + 1 < NS) iw_cur = r_region[ridx + NH];  // prefetch next iw
            if (t == NS - 1) h_last[(size_t)b * NH + i] = hn;
        }
        // no barrier: next poll only rewrites h_lds (reads done pre-barrier);
        // redbuf rewritten only after the next post-poll __syncthreads.
    }
}

// ---------------------------------------------------------------------------
// Kernel 3: output projection  out[b][s][o] = sum_h r[b][s][h]*W_out[o][h] + b_out[o]
// ---------------------------------------------------------------------------
__global__ __launch_bounds__(256)
void k_out_proj(const float* __restrict__ r, const float* __restrict__ W_out,
                const float* __restrict__ b_out, float* __restrict__ out)
{
    const int gid = blockIdx.x * 256 + threadIdx.x;   // < NB*NS*NO = 2^23
    const int o = gid & (NO - 1);
    const int s = (gid >> 6) & (NS - 1);
    const int b = gid >> 18;
    const f4* rr = reinterpret_cast<const f4*>(r + ((size_t)b * NS + s) * NH);
    const f4* wr = reinterpret_cast<const f4*>(W_out + o * NH);
    float acc = b_out[o];
#pragma unroll
    for (int q = 0; q < NH / 4; ++q) {
        const f4 rv = rr[q], wv = wr[q];
        acc = fmaf(rv[0], wv[0], acc); acc = fmaf(rv[1], wv[1], acc);
        acc = fmaf(rv[2], wv[2], acc); acc = fmaf(rv[3], wv[3], acc);
    }
    out[gid] = acc;   // gid == ((b*NS)+s)*NO + o
}

// ---------------------------------------------------------------------------
extern "C" void kernel_launch(void* const* d_in, const int* in_sizes, int n_in,
                              void* d_out, int out_size, void* d_ws, size_t ws_size,
                              hipStream_t stream)
{
    const float* u      = (const float*)d_in[0];
    const float* hidden = (const float*)d_in[1];
    const float* W_in   = (const float*)d_in[2];
    const float* b_in   = (const float*)d_in[3];
    const float* T3     = (const float*)d_in[4];
    const float* bias_t = (const float*)d_in[5];
    const float* W_out  = (const float*)d_in[6];
    const float* b_out  = (const float*)d_in[7];

    float* out_f  = (float*)d_out;
    float* out_y  = out_f;                                  // [B][S][O]
    float* out_hl = out_f + (size_t)NB * NS * NO;           // [B][H]
    float* out_r  = out_hl + (size_t)NB * NH;               // [B][S][H]

    uint64_t* hex = (uint64_t*)d_ws;                        // [2][NH][NB] = 64 KB

    // reset exchange buffer every call (graph-replay safe):
    // 0xFF -> parity-1 epochs 0xFFFFFFFF (never match), then fill parity 0.
    hipMemsetAsync(hex, 0xFF, 2 * NB * NH * sizeof(uint64_t), stream);
    k_init_hex<<<(NB * NH) / 256, 256, 0, stream>>>(hidden, hex);

    k_input_proj<<<(NB * NS * NH) / 256, 256, 0, stream>>>(u, W_in, b_in, out_r);
    k_recur<<<2 * NH, RT, 0, stream>>>(T3, bias_t, out_r, out_hl, hex);
    k_out_proj<<<(NB * NS * NO) / 256, 256, 0, stream>>>(out_r, W_out, b_out, out_y);
}

// Round 15
// 36222.580 us; speedup vs baseline: 1.3529x; 1.0840x over previous
//
#include <hip/hip_runtime.h>
#include <math.h>
#include <stdint.h>

// Three-body RNN: B=32, S=4096, I=64, H=128, O=64
#define NB 32
#define NS 4096
#define NI 64
#define NH 128
#define NO 64
#define RT 256

// Spin-guards: convert any stall into a fast diagnosable wrong-answer
// instead of a device-wedging hang. Phase-1 is a tight loop (~1000cy/iter)
// -> 1<<24 iters ~ 2s worst case. Phase-2 keeps backoff -> 1<<22.
#define SPIN_MAX1 (1 << 24)
#define SPIN_MAX2 (1 << 22)

// h_lds layout: per batch, 16 chunks of 8 floats at stride 12 floats
// (2-way bank aliasing only = free; verified r2-r14)
#define CH_STRIDE 12
#define B_STRIDE (16 * CH_STRIDE)   // 192 floats per batch

typedef float f4 __attribute__((ext_vector_type(4)));
typedef unsigned int u4 __attribute__((ext_vector_type(4)));

// ---------------------------------------------------------------------------
// Kernel 1: input projection  iw[b][t][h] = sum_i u[b][t][i]*W_in[h][i] + b_in[h]
// ---------------------------------------------------------------------------
__global__ __launch_bounds__(256)
void k_input_proj(const float* __restrict__ u, const float* __restrict__ W_in,
                  const float* __restrict__ b_in, float* __restrict__ iw)
{
    const int gid = blockIdx.x * 256 + threadIdx.x;   // < NB*NS*NH = 2^24
    const int h = gid & (NH - 1);
    const int t = (gid >> 7) & (NS - 1);
    const int b = gid >> 19;
    const f4* ur = reinterpret_cast<const f4*>(u + ((size_t)b * NS + t) * NI);
    const f4* wr = reinterpret_cast<const f4*>(W_in + h * NI);
    float acc = b_in[h];
#pragma unroll
    for (int q = 0; q < NI / 4; ++q) {
        const f4 uv = ur[q], wv = wr[q];
        acc = fmaf(uv[0], wv[0], acc); acc = fmaf(uv[1], wv[1], acc);
        acc = fmaf(uv[2], wv[2], acc); acc = fmaf(uv[3], wv[3], acc);
    }
    iw[gid] = acc;   // gid == ((b*NS)+t)*NH + h
}

// ---------------------------------------------------------------------------
// Kernel 1b: init epoch-packed exchange, layout hex[par][i][b].
// parity 0 = (h0, epoch 0); parity-1 slots pre-memset to 0xFF (never match).
// ---------------------------------------------------------------------------
__global__ __launch_bounds__(256)
void k_init_hex(const float* __restrict__ hidden, uint64_t* __restrict__ hex)
{
    const int gid = blockIdx.x * 256 + threadIdx.x;   // < NH*NB = 4096
    const int b = gid & (NB - 1);
    const int i = gid >> 5;
    hex[gid] = (uint64_t)__float_as_uint(hidden[b * NH + i]);  // epoch 0 hi
}

// ---------------------------------------------------------------------------
// Kernel 2: persistent recurrence — r14 structure (passing baseline, 35.2ms)
// with ONE change: phase-1 spins tight (no s_sleep). Detect granularity was
// the one unseparated term of r7's two-phase poll (r7 changed payload 8x AND
// added sleep). 8B payload keeps traffic ~4x below r6's congesting level.
// Block bi = (i = bi>>1, bh = bi&1). T3 tile in 16 NAMED f4 regs (asm
// execute-once; VGPR=132 proven). All exchange at sc0 sc1 (system scope).
// Epoch-packed parity double-buffer; phase-2 verifies all 8 embedded epochs.
// ---------------------------------------------------------------------------
__global__ __launch_bounds__(RT)
__attribute__((amdgpu_waves_per_eu(1, 1)))
void k_recur(const float* __restrict__ T3, const float* __restrict__ bias_t,
             float* __restrict__ r_region,   // [B][S][H]: iw on entry, h on exit
             float* __restrict__ h_last,     // [B][H]
             uint64_t* hex)                  // [2][NH][NB] epoch-packed
{
    const int bi  = blockIdx.x;
    const int i   = bi >> 1;
    const int bh  = bi & 1;
    const int B0  = bh * 16;
    const int tid = threadIdx.x;
    const int jg  = tid >> 4;          // 0..15 (j-group for compute)
    const int kg  = tid & 15;          // 0..15 (k-group for compute)
    const int w   = tid >> 6;          // wave 0..3

    // poll mapping: thread owns line (i_pol, oct) = 8 consecutive b slots
    const int ipol = tid >> 1;                 // 0..127
    const int oct  = 2 * bh + (tid & 1);       // 0..3 (global b-oct)
    const int bl0  = (tid & 1) * 8;            // local b of first slot

    __shared__ float h_lds[16 * B_STRIDE];   // 12 KB
    __shared__ float redbuf[4][16];
    __shared__ float lds_pad[20480];         // pins 1-block/CU reg budget

    // ---- T3 tile -> 16 NAMED f4 registers via volatile asm loads ----
    const float* base = T3 + (size_t)i * NH * NH + (size_t)(jg * 8) * NH + kg * 8;
    f4 t3_0, t3_1, t3_2, t3_3, t3_4, t3_5, t3_6, t3_7;
    f4 t3_8, t3_9, t3_10, t3_11, t3_12, t3_13, t3_14, t3_15;
#define T3LOAD(dst, fofs) \
    asm volatile("global_load_dwordx4 %0, %1, off" \
                 : "=v"(dst) : "v"(base + (fofs)) : "memory")
    T3LOAD(t3_0,  0 * NH);     T3LOAD(t3_1,  0 * NH + 4);
    T3LOAD(t3_2,  1 * NH);     T3LOAD(t3_3,  1 * NH + 4);
    T3LOAD(t3_4,  2 * NH);     T3LOAD(t3_5,  2 * NH + 4);
    T3LOAD(t3_6,  3 * NH);     T3LOAD(t3_7,  3 * NH + 4);
    T3LOAD(t3_8,  4 * NH);     T3LOAD(t3_9,  4 * NH + 4);
    T3LOAD(t3_10, 5 * NH);     T3LOAD(t3_11, 5 * NH + 4);
    T3LOAD(t3_12, 6 * NH);     T3LOAD(t3_13, 6 * NH + 4);
    T3LOAD(t3_14, 7 * NH);     T3LOAD(t3_15, 7 * NH + 4);
#undef T3LOAD
    asm volatile("s_waitcnt vmcnt(0)" ::: "memory");
    __builtin_amdgcn_sched_barrier(0);

    const float bias = bias_t[i];
    // runtime-impossible guard keeps lds_pad allocated without executing
    if (bias > 1.0e30f) lds_pad[tid] = bias;

    float iw_cur = 0.f;
    if (tid < 16)
        iw_cur = r_region[((size_t)(B0 + tid) * NS + 0) * NH + i];

    for (int t = 0; t < NS; ++t) {
        // ---- two-phase poll of own 64B line (system scope) ----
        {
            const uint64_t* src = hex + ((size_t)(t & 1) * NH + ipol) * NB + oct * 8;
            const uint32_t et = (uint32_t)t;
            // phase 1: cheap 8B spin on slot-0 epoch — TIGHT (no sleep):
            // detect granularity = one load RT instead of RT + backoff
            uint64_t s0v;
            for (int spin = 0;; ++spin) {
                asm volatile("global_load_dwordx2 %0, %1, off sc0 sc1\n\t"
                             "s_waitcnt vmcnt(0)"
                             : "=v"(s0v) : "v"(src) : "memory");
                if (((uint32_t)(s0v >> 32) == et) | (spin > SPIN_MAX1)) break;
            }
            // phase 2: full line, verify ALL epochs (no atomicity assumption)
            u4 q0, q1, q2, q3;
            for (int spin = 0;; ++spin) {
                asm volatile(
                    "global_load_dwordx4 %0, %4, off sc0 sc1\n\t"
                    "global_load_dwordx4 %1, %4, off offset:16 sc0 sc1\n\t"
                    "global_load_dwordx4 %2, %4, off offset:32 sc0 sc1\n\t"
                    "global_load_dwordx4 %3, %4, off offset:48 sc0 sc1\n\t"
                    "s_waitcnt vmcnt(0)"
                    : "=&v"(q0), "=&v"(q1), "=&v"(q2), "=&v"(q3)
                    : "v"(src) : "memory");
                if ((q0[1] == et && q0[3] == et && q1[1] == et && q1[3] == et &&
                     q2[1] == et && q2[3] == et && q3[1] == et && q3[3] == et)
                    | (spin > SPIN_MAX2))
                    break;
                asm volatile("s_sleep 1");
            }
            // scatter 8 b-rows of h[i=ipol] into LDS
            float* dst = h_lds + bl0 * B_STRIDE
                       + (ipol >> 3) * CH_STRIDE + (ipol & 7);
            dst[0 * B_STRIDE] = __uint_as_float(q0[0]);
            dst[1 * B_STRIDE] = __uint_as_float(q0[2]);
            dst[2 * B_STRIDE] = __uint_as_float(q1[0]);
            dst[3 * B_STRIDE] = __uint_as_float(q1[2]);
            dst[4 * B_STRIDE] = __uint_as_float(q2[0]);
            dst[5 * B_STRIDE] = __uint_as_float(q2[2]);
            dst[6 * B_STRIDE] = __uint_as_float(q3[0]);
            dst[7 * B_STRIDE] = __uint_as_float(q3[2]);
        }
        __syncthreads();

        // ---- compute: 16 batches, T3 in named regs, explicit unroll ----
#define JJBODY(tA, tB, HJV) \
        { float s0 = 0.f, s1 = 0.f; \
          s0 = fmaf(tA[0], hk0[0], s0); s1 = fmaf(tA[1], hk0[1], s1); \
          s0 = fmaf(tA[2], hk0[2], s0); s1 = fmaf(tA[3], hk0[3], s1); \
          s0 = fmaf(tB[0], hk1[0], s0); s1 = fmaf(tB[1], hk1[1], s1); \
          s0 = fmaf(tB[2], hk1[2], s0); s1 = fmaf(tB[3], hk1[3], s1); \
          acc = fmaf(HJV, s0 + s1, acc); }
#pragma unroll 4
        for (int b = 0; b < 16; ++b) {
            const float* row = h_lds + b * B_STRIDE;
            const f4 hj0 = *reinterpret_cast<const f4*>(row + jg * CH_STRIDE);
            const f4 hj1 = *reinterpret_cast<const f4*>(row + jg * CH_STRIDE + 4);
            const f4 hk0 = *reinterpret_cast<const f4*>(row + kg * CH_STRIDE);
            const f4 hk1 = *reinterpret_cast<const f4*>(row + kg * CH_STRIDE + 4);
            float acc = 0.f;
            JJBODY(t3_0,  t3_1,  hj0[0]);
            JJBODY(t3_2,  t3_3,  hj0[1]);
            JJBODY(t3_4,  t3_5,  hj0[2]);
            JJBODY(t3_6,  t3_7,  hj0[3]);
            JJBODY(t3_8,  t3_9,  hj1[0]);
            JJBODY(t3_10, t3_11, hj1[1]);
            JJBODY(t3_12, t3_13, hj1[2]);
            JJBODY(t3_14, t3_15, hj1[3]);
            acc += __shfl_xor(acc, 1);  acc += __shfl_xor(acc, 2);
            acc += __shfl_xor(acc, 4);  acc += __shfl_xor(acc, 8);
            acc += __shfl_xor(acc, 16); acc += __shfl_xor(acc, 32);
            if ((tid & 63) == b) redbuf[w][b] = acc;
        }
#undef JJBODY
        __syncthreads();

        // ---- finalize: 16 lanes of wave 0, one batch each ----
        if (tid < 16) {
            const int b = B0 + tid;
            const float s = redbuf[0][tid] + redbuf[1][tid]
                          + redbuf[2][tid] + redbuf[3][tid];
            const float hn = tanhf(s + bias + iw_cur);
            // coalesced contiguous release: 16 lanes -> 2 full 64B lines,
            // system scope (write-through to coherence point)
            const uint64_t pv = ((uint64_t)(uint32_t)(t + 1) << 32)
                              | (uint64_t)__float_as_uint(hn);
            uint64_t* dstp = hex + ((size_t)((t + 1) & 1) * NH + i) * NB + b;
            asm volatile("global_store_dwordx2 %0, %1, off sc0 sc1"
                         :: "v"(dstp), "v"(pv) : "memory");
            const size_t ridx = ((size_t)b * NS + t) * NH + i;
            r_region[ridx] = hn;
            if (t + 1 < NS) iw_cur = r_region[ridx + NH];  // prefetch next iw
            if (t == NS - 1) h_last[(size_t)b * NH + i] = hn;
        }
        // no barrier: next poll only rewrites h_lds (reads done pre-barrier);
        // redbuf rewritten only after the next post-poll __syncthreads.
    }
}

// ---------------------------------------------------------------------------
// Kernel 3: output projection  out[b][s][o] = sum_h r[b][s][h]*W_out[o][h] + b_out[o]
// ---------------------------------------------------------------------------
__global__ __launch_bounds__(256)
void k_out_proj(const float* __restrict__ r, const float* __restrict__ W_out,
                const float* __restrict__ b_out, float* __restrict__ out)
{
    const int gid = blockIdx.x * 256 + threadIdx.x;   // < NB*NS*NO = 2^23
    const int o = gid & (NO - 1);
    const int s = (gid >> 6) & (NS - 1);
    const int b = gid >> 18;
    const f4* rr = reinterpret_cast<const f4*>(r + ((size_t)b * NS + s) * NH);
    const f4* wr = reinterpret_cast<const f4*>(W_out + o * NH);
    float acc = b_out[o];
#pragma unroll
    for (int q = 0; q < NH / 4; ++q) {
        const f4 rv = rr[q], wv = wr[q];
        acc = fmaf(rv[0], wv[0], acc); acc = fmaf(rv[1], wv[1], acc);
        acc = fmaf(rv[2], wv[2], acc); acc = fmaf(rv[3], wv[3], acc);
    }
    out[gid] = acc;   // gid == ((b*NS)+s)*NO + o
}

// ---------------------------------------------------------------------------
extern "C" void kernel_launch(void* const* d_in, const int* in_sizes, int n_in,
                              void* d_out, int out_size, void* d_ws, size_t ws_size,
                              hipStream_t stream)
{
    const float* u      = (const float*)d_in[0];
    const float* hidden = (const float*)d_in[1];
    const float* W_in   = (const float*)d_in[2];
    const float* b_in   = (const float*)d_in[3];
    const float* T3     = (const float*)d_in[4];
    const float* bias_t = (const float*)d_in[5];
    const float* W_out  = (const float*)d_in[6];
    const float* b_out  = (const float*)d_in[7];

    float* out_f  = (float*)d_out;
    float* out_y  = out_f;                                  // [B][S][O]
    float* out_hl = out_f + (size_t)NB * NS * NO;           // [B][H]
    float* out_r  = out_hl + (size_t)NB * NH;               // [B][S][H]

    uint64_t* hex = (uint64_t*)d_ws;                        // [2][NH][NB] = 64 KB

    // reset exchange buffer every call (graph-replay safe):
    // 0xFF -> parity-1 epochs 0xFFFFFFFF (never match), then fill parity 0.
    hipMemsetAsync(hex, 0xFF, 2 * NB * NH * sizeof(uint64_t), stream);
    k_init_hex<<<(NB * NH) / 256, 256, 0, stream>>>(hidden, hex);

    k_input_proj<<<(NB * NS * NH) / 256, 256, 0, stream>>>(u, W_in, b_in, out_r);
    k_recur<<<2 * NH, RT, 0, stream>>>(T3, bias_t, out_r, out_hl, hex);
    k_out_proj<<<(NB * NS * NO) / 256, 256, 0, stream>>>(out_r, W_out, b_out, out_y);
}